// Round 1
// 503.473 us; speedup vs baseline: 1.0372x; 1.0372x over previous
//
#include <hip/hip_runtime.h>

typedef __bf16 bfrag __attribute__((ext_vector_type(8)));
typedef float f32x4 __attribute__((ext_vector_type(4)));

#define GLDS16(g, l) __builtin_amdgcn_global_load_lds( \
    (__attribute__((address_space(1))) void*)(g),      \
    (__attribute__((address_space(3))) void*)(l), 16, 0, 0)

__device__ __forceinline__ float bf2f(ushort u) {
    return __uint_as_float(((unsigned)u) << 16);
}
__device__ __forceinline__ ushort f2bf(float f) {
    unsigned u = __float_as_uint(f);
    u += 0x7fff + ((u >> 16) & 1);
    return (ushort)(u >> 16);
}
__device__ __forceinline__ float sigmoidf_(float v) {
    return 1.0f / (1.0f + expf(-v));
}

// ---------------- merged prep: castcat + all transposes + bias concat ----------------
struct TD { const float* src; ushort* dst; int src_ld; int dst_ld; int ktiles; int off; };
struct TA { TD d[6]; };

__global__ __launch_bounds__(256) void k_prep(const float* __restrict__ x,
                                              const float* __restrict__ h,
                                              const float* __restrict__ c,
                                              ushort* __restrict__ xhcb, TA a,
                                              const float* __restrict__ bi,
                                              const float* __restrict__ bf_,
                                              const float* __restrict__ bc,
                                              const float* __restrict__ bo,
                                              float* __restrict__ Biasf) {
    __shared__ float tile[64][65];
    int bid = blockIdx.x;
    int t = threadIdx.x;
    if (bid < 12288) {
        // castcat: xhcb[b][0:3072] = bf16([x|h|c][b]), 8 elems/thread
        int idx = bid * 256 + t;
        int row = idx / 384;
        int c8 = (idx - row * 384) * 8;
        const float* s = (c8 < 1024) ? &x[(size_t)row * 1024 + c8]
                       : (c8 < 2048) ? &h[(size_t)row * 1024 + (c8 - 1024)]
                                     : &c[(size_t)row * 1024 + (c8 - 2048)];
        float4 va = *(const float4*)s;
        float4 vb = *(const float4*)(s + 4);
        ushort tmp[8] = {f2bf(va.x), f2bf(va.y), f2bf(va.z), f2bf(va.w),
                         f2bf(vb.x), f2bf(vb.y), f2bf(vb.z), f2bf(vb.w)};
        *(uint4*)&xhcb[(size_t)idx * 8] = *(uint4*)tmp;
    } else if (bid < 15120) {
        // transpose+cast: dst[n*dst_ld + k] = bf16(src[k*src_ld + n])
        int tb = bid - 12288;
        int ri = 0;
#pragma unroll
        for (int i = 1; i < 6; ++i) ri = (tb >= a.d[i].off) ? i : ri;
        const float* src = a.d[ri].src;
        ushort* dst = a.d[ri].dst;
        int src_ld = a.d[ri].src_ld, dst_ld = a.d[ri].dst_ld;
        int local = tb - a.d[ri].off;
        int bx = local % a.d[ri].ktiles;
        int by = local / a.d[ri].ktiles;
        int k0 = bx * 64, n0 = by * 64;
        int c4 = (t & 15) * 4;
        int r = t >> 4;
#pragma unroll
        for (int i = 0; i < 4; ++i) {
            int rr = r + i * 16;
            float4 v = *(const float4*)&src[(size_t)(k0 + rr) * src_ld + n0 + c4];
            tile[rr][c4 + 0] = v.x; tile[rr][c4 + 1] = v.y;
            tile[rr][c4 + 2] = v.z; tile[rr][c4 + 3] = v.w;
        }
        __syncthreads();
        int kk8 = (t & 7) * 8;
        int nn = t >> 3;
#pragma unroll
        for (int i = 0; i < 2; ++i) {
            int n = nn + i * 32;
            ushort tmp[8];
#pragma unroll
            for (int j = 0; j < 8; ++j) tmp[j] = f2bf(tile[kk8 + j][n]);
            *(uint4*)&dst[(size_t)(n0 + n) * dst_ld + k0 + kk8] = *(uint4*)tmp;
        }
    } else {
        int idx = (bid - 15120) * 256 + t;  // 0..4095
        int g = idx >> 10, n = idx & 1023;
        const float* s = (g == 0) ? bi : (g == 1) ? bf_ : (g == 2) ? bc : bo;
        Biasf[idx] = s[n];
    }
}

// ---------------- GEMM1: 256x256 tile, BK=64, 8 waves, deep-pipelined ----------------
// Per K-tile: 4 phases (qm,qn quadrants of each wave's 128x64 C block).
// Stage schedule (quarter-tile freeing, all gaps >= 4 phases):
//   tile t p1: stage A-part1(t+1) -> buf (t+1)&1   (old qm=1 rows died end of t-1)
//   tile t p2: stage B-part1(t+1) -> buf (t+1)&1   (old qn=1 rows died end of t-1)
//   tile t p3: stage A-part0(t+2) -> buf t&1       (qm=0 rows freed end of p2)
//   tile t p4: stage B-part0(t+2) -> buf t&1       (qn=0 rows freed end of p3)
// Boundary wait once per tile: vmcnt(4) leaves exactly the p3/p4 stages in flight.
// A LDS: identity rows [0..255]; part0={0-63,128-191}, part1={64-127,192-255}.
// B LDS: permuted rows, LDS row (qn*128 + wc*32 + jj*16 + l16) holds global col
//        n0 + wc*64 + qn*32 + jj*16 + l16. Both sides keep the kg^(row&7) swizzle.
__global__ __launch_bounds__(512) void k_gemm1(const ushort* __restrict__ xhcb,
                                               const ushort* __restrict__ WT,
                                               const float* __restrict__ bias,
                                               ushort* __restrict__ Pre) {
    __shared__ __align__(16) ushort lds[2][32768];  // per buf: A 16384, B 16384 (128 KiB)
    const int t = threadIdx.x;
    const int m0 = blockIdx.x * 256;
    const int by = blockIdx.y;
    const int n0 = by * 256;
    const int KTOT = (by < 8) ? 3072 : 2048;
    const int NT = KTOT >> 6;
    const int w = t >> 6, l = t & 63;
    const int wr = w >> 2, wc = w & 3;  // 2 (M) x 4 (N) waves
    const int lane16 = l & 15, quad = l >> 4;
    const int r7 = lane16 & 7;
    const int rowt = t >> 3;            // 0..63 staging row within 64-row round
    const int kg = (t & 7) ^ (rowt & 7);  // swizzled source 16B k-group
    const int brow_hi = rowt >> 5, brow_lo = rowt & 31;
    f32x4 acc[8][4] = {};

    const ushort* Ag = xhcb + (size_t)(m0 + rowt) * 3072 + kg * 8;
    const ushort* Bg = WT + (size_t)(n0 + brow_lo) * 3072 + kg * 8;

#define STAGE_A(BUF, PI, KT)                                                       \
    do {                                                                           \
        GLDS16(Ag + (size_t)((PI) * 64) * 3072 + (KT) * 64,                        \
               &lds[BUF][((PI) * 64) * 64] + t * 8);                               \
        GLDS16(Ag + (size_t)((PI) * 64 + 128) * 3072 + (KT) * 64,                  \
               &lds[BUF][((PI) * 64 + 128) * 64] + t * 8);                         \
    } while (0)

#define STAGE_B(BUF, PI, KT)                                                       \
    do {                                                                           \
        GLDS16(Bg + (size_t)((PI) * 32 + brow_hi * 64) * 3072 + (KT) * 64,         \
               &lds[BUF][16384 + ((PI) * 128) * 64] + t * 8);                      \
        GLDS16(Bg + (size_t)((PI) * 32 + (2 + brow_hi) * 64) * 3072 + (KT) * 64,   \
               &lds[BUF][16384 + ((PI) * 128 + 64) * 64] + t * 8);                 \
    } while (0)

#define PHASE(QM, QN, STAGE_CODE, TAIL_CODE)                                              \
    do {                                                                                  \
        bfrag af[4][2], bfv[2][2];                                                        \
        _Pragma("unroll") for (int ii = 0; ii < 4; ++ii) {                                \
            _Pragma("unroll") for (int h = 0; h < 2; ++h)                                 \
                af[ii][h] = *(const bfrag*)&Acur[(wr * 128 + (QM) * 64 + ii * 16 + lane16) * 64 + \
                                                 (((h * 4 + quad) ^ r7) * 8)];            \
        }                                                                                 \
        _Pragma("unroll") for (int jj = 0; jj < 2; ++jj) {                                \
            _Pragma("unroll") for (int h = 0; h < 2; ++h)                                 \
                bfv[jj][h] = *(const bfrag*)&Bcur[((QN) * 128 + wc * 32 + jj * 16 + lane16) * 64 + \
                                                  (((h * 4 + quad) ^ r7) * 8)];           \
        }                                                                                 \
        STAGE_CODE;                                                                       \
        __builtin_amdgcn_s_barrier();                                                     \
        asm volatile("s_waitcnt lgkmcnt(0)" ::: "memory");                                \
        __builtin_amdgcn_s_setprio(1);                                                    \
        _Pragma("unroll") for (int ii = 0; ii < 4; ++ii) {                                \
            _Pragma("unroll") for (int jj = 0; jj < 2; ++jj) {                            \
                _Pragma("unroll") for (int h = 0; h < 2; ++h)                             \
                    acc[(QM) * 4 + ii][(QN) * 2 + jj] =                                   \
                        __builtin_amdgcn_mfma_f32_16x16x32_bf16(                          \
                            af[ii][h], bfv[jj][h], acc[(QM) * 4 + ii][(QN) * 2 + jj],     \
                            0, 0, 0);                                                     \
            }                                                                             \
        }                                                                                 \
        __builtin_amdgcn_s_setprio(0);                                                    \
        TAIL_CODE;                                                                        \
        __builtin_amdgcn_s_barrier();                                                     \
    } while (0)

    // prologue: tile0 complete + tile1 part0s; first 8 loads must land -> vmcnt(4)
    STAGE_A(0, 0, 0); STAGE_B(0, 0, 0);
    STAGE_A(0, 1, 0); STAGE_B(0, 1, 0);
    STAGE_A(1, 0, 1); STAGE_B(1, 0, 1);
    asm volatile("s_waitcnt vmcnt(4)" ::: "memory");
    __builtin_amdgcn_s_barrier();

    for (int kt = 0; kt < NT; ++kt) {
        const int cur = kt & 1;
        const int nxt = cur ^ 1;
        const ushort* Acur = &lds[cur][0];
        const ushort* Bcur = Acur + 16384;
        PHASE(0, 0, { if (kt + 1 < NT) STAGE_A(nxt, 1, kt + 1); }, {});
        PHASE(0, 1, { if (kt + 1 < NT) STAGE_B(nxt, 1, kt + 1); }, {});
        PHASE(1, 0, { if (kt + 2 < NT) STAGE_A(cur, 0, kt + 2); }, {});
        PHASE(1, 1, { if (kt + 2 < NT) STAGE_B(cur, 0, kt + 2); },
              {
                  if (kt + 2 < NT) {
                      asm volatile("s_waitcnt vmcnt(4)" ::: "memory");
                  } else if (kt + 1 < NT) {
                      asm volatile("s_waitcnt vmcnt(0)" ::: "memory");
                  }
              });
    }
#undef PHASE
#undef STAGE_A
#undef STAGE_B

#pragma unroll
    for (int i = 0; i < 8; ++i) {
#pragma unroll
        for (int jj = 0; jj < 4; ++jj) {
            int col = n0 + wc * 64 + (jj >> 1) * 32 + (jj & 1) * 16 + lane16;
            float bv = bias[col];
            int rbase = m0 + wr * 128 + i * 16 + quad * 4;
#pragma unroll
            for (int r = 0; r < 4; ++r)
                Pre[(size_t)(rbase + r) * 4096 + col] = f2bf(acc[i][jj][r] + bv);
        }
    }
}

// ---------------- c_new = sigmoid(f)*c + sigmoid(i)*tanh(cand) ----------------
__global__ __launch_bounds__(256) void k_cnew(const ushort* __restrict__ Pre,
                                              const float* __restrict__ cin,
                                              ushort* __restrict__ Cnewb,
                                              float* __restrict__ out) {
    int idx8 = blockIdx.x * 256 + threadIdx.x;  // 1,048,576 total
    int b = idx8 >> 7;
    int n8 = (idx8 & 127) * 8;
    uint4 vi = *(const uint4*)(Pre + (size_t)b * 4096 + n8);
    uint4 vf = *(const uint4*)(Pre + (size_t)b * 4096 + 1024 + n8);
    uint4 vc = *(const uint4*)(Pre + (size_t)b * 4096 + 2048 + n8);
    float4 c0 = *(const float4*)(cin + (size_t)b * 1024 + n8);
    float4 c1 = *(const float4*)(cin + (size_t)b * 1024 + n8 + 4);
    const ushort* pi = (const ushort*)&vi;
    const ushort* pf = (const ushort*)&vf;
    const ushort* pc = (const ushort*)&vc;
    float cv[8] = {c0.x, c0.y, c0.z, c0.w, c1.x, c1.y, c1.z, c1.w};
    float cn[8];
    ushort cb[8];
#pragma unroll
    for (int j = 0; j < 8; ++j) {
        float iv = sigmoidf_(bf2f(pi[j]));
        float fv = sigmoidf_(bf2f(pf[j]));
        float cp = tanhf(bf2f(pc[j]));
        cn[j] = fv * cv[j] + iv * cp;
        cb[j] = f2bf(cn[j]);
    }
    *(uint4*)(Cnewb + (size_t)b * 1024 + n8) = *(uint4*)cb;
    float* orow = out + (size_t)b * 2050 + 1024 + n8;  // 8B-aligned
#pragma unroll
    for (int j = 0; j < 4; ++j)
        *(float2*)(orow + j * 2) = make_float2(cn[j * 2], cn[j * 2 + 1]);
}

// ---------------- GEMM2: o_pre = Pre_o + c_new @ W_o[2048:]; h_new = sig(o)*tanh(c_new)
__global__ __launch_bounds__(256) void k_gemm2(const ushort* __restrict__ Cnewb,
                                               const ushort* __restrict__ WoCT,
                                               const ushort* __restrict__ Pre,
                                               ushort* __restrict__ Hnewb,
                                               float* __restrict__ out) {
    __shared__ __align__(16) ushort As[128 * 64];
    __shared__ __align__(16) ushort Bs[128 * 64];
    int t = threadIdx.x;
    int m0 = blockIdx.x * 128, n0 = blockIdx.y * 128;
    int w = t >> 6, l = t & 63;
    int wm = (w & 1) * 64, wn = (w >> 1) * 64;
    int lane16 = l & 15, quad = l >> 4;
    int rowt = t >> 3;
    int kg = (t & 7) ^ (rowt & 7);
    int r7 = lane16 & 7;
    f32x4 acc[4][4] = {};

    const ushort* Abase = Cnewb + (size_t)(m0 + rowt) * 1024 + kg * 8;
    const ushort* Bbase = WoCT + (size_t)(n0 + rowt) * 1024 + kg * 8;

    for (int k0 = 0; k0 < 1024; k0 += 64) {
#pragma unroll
        for (int q = 0; q < 4; ++q)
            GLDS16(Abase + (size_t)q * 32 * 1024 + k0, As + q * 2048 + t * 8);
#pragma unroll
        for (int q = 0; q < 4; ++q)
            GLDS16(Bbase + (size_t)q * 32 * 1024 + k0, Bs + q * 2048 + t * 8);
        __syncthreads();
#pragma unroll
        for (int hh = 0; hh < 2; ++hh) {
            int slot8 = ((hh * 4 + quad) ^ r7) * 8;
            bfrag af[4], bfr[4];
#pragma unroll
            for (int i = 0; i < 4; ++i) {
                af[i]  = *(const bfrag*)&As[(wm + i * 16 + lane16) * 64 + slot8];
                bfr[i] = *(const bfrag*)&Bs[(wn + i * 16 + lane16) * 64 + slot8];
            }
#pragma unroll
            for (int i = 0; i < 4; ++i)
#pragma unroll
                for (int j = 0; j < 4; ++j)
                    acc[i][j] = __builtin_amdgcn_mfma_f32_16x16x32_bf16(af[i], bfr[j], acc[i][j], 0, 0, 0);
        }
        __syncthreads();
    }
#pragma unroll
    for (int i = 0; i < 4; ++i) {
#pragma unroll
        for (int j = 0; j < 4; ++j) {
            int col = n0 + wn + j * 16 + lane16;
            int rbase = m0 + wm + i * 16 + quad * 4;
#pragma unroll
            for (int r = 0; r < 4; ++r) {
                int row = rbase + r;
                float opre = acc[i][j][r] + bf2f(Pre[(size_t)row * 4096 + 3072 + col]);
                float o = sigmoidf_(opre);
                float cnv = bf2f(Cnewb[(size_t)row * 1024 + col]);
                float hv = o * tanhf(cnv);
                Hnewb[(size_t)row * 1024 + col] = f2bf(hv);
                out[(size_t)row * 2050 + col] = hv;
            }
        }
    }
}

// ---------------- attention + gumbel + alpha/beta (16 rows per block) ----------------
__global__ __launch_bounds__(256) void k_attn(
    const ushort* __restrict__ Hnewb, const float* __restrict__ outr,
    const float* __restrict__ x, const float* __restrict__ memory,
    const float* __restrict__ u_gs, const float* __restrict__ u_a,
    const float* __restrict__ u_b, const ushort* __restrict__ WmT,
    const float* __restrict__ b_m,
    const float* __restrict__ w_a_h, const float* __restrict__ w_a_x,
    const float* __restrict__ w_a_r, const float* __restrict__ w_b_h,
    const float* __restrict__ w_b_x, const float* __restrict__ w_b_r,
    float* __restrict__ out) {
    __shared__ float sMicro[16 * 64];
    __shared__ float sAttn[16 * 16];
    __shared__ float sSamp[16 * 64];

    int b0 = blockIdx.x * 16;
    int t = threadIdx.x;
    int w = t >> 6, l = t & 63;
    int lane16 = l & 15, quad = l >> 4;

    // wave w computes micro[0:16][16w:16w+16] via MFMA
    {
        f32x4 acc = {0.f, 0.f, 0.f, 0.f};
        const ushort* Ab = Hnewb + (size_t)(b0 + lane16) * 1024 + quad * 8;
        const ushort* Bb = WmT + (size_t)(w * 16 + lane16) * 1024 + quad * 8;
#pragma unroll 4
        for (int k0 = 0; k0 < 1024; k0 += 32) {
            bfrag av = *(const bfrag*)(Ab + k0);
            bfrag bv = *(const bfrag*)(Bb + k0);
            acc = __builtin_amdgcn_mfma_f32_16x16x32_bf16(av, bv, acc, 0, 0, 0);
        }
        float bm = b_m[w * 16 + lane16];
#pragma unroll
        for (int r = 0; r < 4; ++r)
            sMicro[(quad * 4 + r) * 64 + w * 16 + lane16] = acc[r] + bm;
    }
    __syncthreads();

    // logits + gumbel softmax over M=16
    {
        int r = t >> 4, m = t & 15;
        const float4* mem4 = (const float4*)(memory + (size_t)(b0 + r) * 1024 + m * 64);
        float lg = 0.f;
#pragma unroll
        for (int k4 = 0; k4 < 16; ++k4) {
            float4 mv = mem4[k4];
            const float* sm = &sMicro[r * 64 + k4 * 4];
            lg += mv.x * sm[0] + mv.y * sm[1] + mv.z * sm[2] + mv.w * sm[3];
        }
        float u = u_gs[(b0 + r) * 16 + m];
        float z = lg - logf(-logf(u));  // TAU = 1
        float zm = z;
        for (int off = 8; off; off >>= 1) zm = fmaxf(zm, __shfl_xor(zm, off, 16));
        float p = expf(z - zm);
        float ps = p;
        for (int off = 8; off; off >>= 1) ps += __shfl_xor(ps, off, 16);
        sAttn[r * 16 + m] = p / ps;
    }
    __syncthreads();

    // sampled = memory^T @ attn + 1
#pragma unroll
    for (int q = 0; q < 4; ++q) {
        int r = w * 4 + q;
        const float* mem = memory + (size_t)(b0 + r) * 1024 + l;
        float s = 0.f;
#pragma unroll
        for (int m = 0; m < 16; ++m) s += sAttn[r * 16 + m] * mem[m * 64];
        sSamp[r * 64 + l] = s + 1.0f;
    }
    __syncthreads();

    // alpha / beta
    {
        int r = t >> 4, s16 = t & 15;
        size_t hoff = (size_t)(b0 + r) * 2050;
        size_t xoff = (size_t)(b0 + r) * 1024;
        float za = 0.f, zb = 0.f;
        for (int kk = 0; kk < 64; ++kk) {
            int k = s16 + kk * 16;
            float hv = outr[hoff + k];
            float xv = x[xoff + k];
            za += hv * w_a_h[k] + xv * w_a_x[k];
            zb += hv * w_b_h[k] + xv * w_b_x[k];
        }
#pragma unroll
        for (int k = s16 * 4; k < s16 * 4 + 4; ++k) {
            float sv = sSamp[r * 64 + k];
            za += sv * w_a_r[k];
            zb += sv * w_b_r[k];
        }
        for (int off = 8; off; off >>= 1) {
            za += __shfl_xor(za, off, 16);
            zb += __shfl_xor(zb, off, 16);
        }
        if (s16 == 0) {
            float ua = u_a[b0 + r];
            float ub = u_b[b0 + r];
            float la = logf(ua) - log1pf(-ua);
            float lb = logf(ub) - log1pf(-ub);
            out[(size_t)(b0 + r) * 2050 + 2048] = sigmoidf_(za + la);
            out[(size_t)(b0 + r) * 2050 + 2049] = sigmoidf_(zb + lb);
        }
    }
}

extern "C" void kernel_launch(void* const* d_in, const int* in_sizes, int n_in,
                              void* d_out, int out_size, void* d_ws, size_t ws_size,
                              hipStream_t stream) {
    const float* x      = (const float*)d_in[0];
    const float* h      = (const float*)d_in[1];
    const float* c      = (const float*)d_in[2];
    const float* memory = (const float*)d_in[3];
    const float* u_gs   = (const float*)d_in[4];
    const float* u_a    = (const float*)d_in[5];
    const float* u_b    = (const float*)d_in[6];
    const float* W_i    = (const float*)d_in[7];
    const float* b_i    = (const float*)d_in[8];
    const float* W_f    = (const float*)d_in[9];
    const float* b_f    = (const float*)d_in[10];
    const float* W_o    = (const float*)d_in[11];
    const float* b_o    = (const float*)d_in[12];
    const float* W_cand = (const float*)d_in[13];
    const float* b_cand = (const float*)d_in[14];
    const float* W_m    = (const float*)d_in[15];
    const float* b_m    = (const float*)d_in[16];
    const float* w_a_h  = (const float*)d_in[17];
    const float* w_a_x  = (const float*)d_in[18];
    const float* w_a_r  = (const float*)d_in[19];
    const float* w_b_h  = (const float*)d_in[20];
    const float* w_b_x  = (const float*)d_in[21];
    const float* w_b_r  = (const float*)d_in[22];
    float* out = (float*)d_out;

    // workspace carve (bytes)
    char* ws = (char*)d_ws;
    ushort* WT    = (ushort*)(ws);                 // 25,165,824
    ushort* WoCT  = (ushort*)(ws + 25165824);      //  2,097,152
    ushort* Pre   = (ushort*)(ws + 27262976);      // 67,108,864
    ushort* xhcb  = (ushort*)(ws + 94371840);      // 50,331,648
    float*  Biasf = (float*)(ws + 144703488);      //     16,384
    ushort* WmT   = (ushort*)(ws + 144719872);     //    131,072
    ushort* Cnewb = xhcb;                          // alias: xhcb dead after gemm1
    ushort* Hnewb = WT;                            // alias: WT dead after gemm1

    TA ta;
    ta.d[0] = {W_i,                       WT,                        1024, 3072, 48, 0};
    ta.d[1] = {W_f,                       WT + (size_t)1024 * 3072,  1024, 3072, 48, 768};
    ta.d[2] = {W_cand,                    WT + (size_t)2048 * 3072,  1024, 3072, 32, 1536};
    ta.d[3] = {W_o,                       WT + (size_t)3072 * 3072,  1024, 3072, 32, 2048};  // first 2048 rows used
    ta.d[4] = {W_o + (size_t)2048 * 1024, WoCT,                      1024, 1024, 16, 2560};
    ta.d[5] = {W_m,                       WmT,                         64, 1024, 16, 2816};  // 16 blocks only

    k_prep<<<15136, 256, 0, stream>>>(x, h, c, xhcb, ta, b_i, b_f, b_cand, b_o, Biasf);

    // fused gemm1: by<8 -> K=3072 (i,f gates), by>=8 -> K=2048 (cand, o-partial)
    k_gemm1<<<dim3(32, 16), 512, 0, stream>>>(xhcb, WT, Biasf, Pre);
    k_cnew<<<4096, 256, 0, stream>>>(Pre, c, Cnewb, out);
    k_gemm2<<<dim3(64, 8), 256, 0, stream>>>(Cnewb, WoCT, Pre, Hnewb, out);
    k_attn<<<512, 256, 0, stream>>>(Hnewb, out, x, memory, u_gs, u_a, u_b, WmT, b_m,
                                    w_a_h, w_a_x, w_a_r, w_b_h, w_b_x, w_b_r, out);
}

// Round 2
// 479.641 us; speedup vs baseline: 1.0887x; 1.0497x over previous
//
#include <hip/hip_runtime.h>

typedef __bf16 bfrag __attribute__((ext_vector_type(8)));
typedef float f32x4 __attribute__((ext_vector_type(4)));

#define GLDS16(g, l) __builtin_amdgcn_global_load_lds( \
    (__attribute__((address_space(1))) void*)(g),      \
    (__attribute__((address_space(3))) void*)(l), 16, 0, 0)

__device__ __forceinline__ float bf2f(ushort u) {
    return __uint_as_float(((unsigned)u) << 16);
}
__device__ __forceinline__ ushort f2bf(float f) {
    unsigned u = __float_as_uint(f);
    u += 0x7fff + ((u >> 16) & 1);
    return (ushort)(u >> 16);
}
__device__ __forceinline__ float sigmoidf_(float v) {
    return 1.0f / (1.0f + expf(-v));
}

// ---------------- merged prep: castcat + all transposes + bias concat ----------------
struct TD { const float* src; ushort* dst; int src_ld; int dst_ld; int ktiles; int off; };
struct TA { TD d[6]; };

__global__ __launch_bounds__(256) void k_prep(const float* __restrict__ x,
                                              const float* __restrict__ h,
                                              const float* __restrict__ c,
                                              ushort* __restrict__ xhcb, TA a,
                                              const float* __restrict__ bi,
                                              const float* __restrict__ bf_,
                                              const float* __restrict__ bc,
                                              const float* __restrict__ bo,
                                              float* __restrict__ Biasf) {
    __shared__ float tile[64][65];
    int bid = blockIdx.x;
    int t = threadIdx.x;
    if (bid < 12288) {
        // castcat: xhcb[b][0:3072] = bf16([x|h|c][b]), 8 elems/thread
        int idx = bid * 256 + t;
        int row = idx / 384;
        int c8 = (idx - row * 384) * 8;
        const float* s = (c8 < 1024) ? &x[(size_t)row * 1024 + c8]
                       : (c8 < 2048) ? &h[(size_t)row * 1024 + (c8 - 1024)]
                                     : &c[(size_t)row * 1024 + (c8 - 2048)];
        float4 va = *(const float4*)s;
        float4 vb = *(const float4*)(s + 4);
        ushort tmp[8] = {f2bf(va.x), f2bf(va.y), f2bf(va.z), f2bf(va.w),
                         f2bf(vb.x), f2bf(vb.y), f2bf(vb.z), f2bf(vb.w)};
        *(uint4*)&xhcb[(size_t)idx * 8] = *(uint4*)tmp;
    } else if (bid < 15120) {
        // transpose+cast: dst[n*dst_ld + k] = bf16(src[k*src_ld + n])
        int tb = bid - 12288;
        int ri = 0;
#pragma unroll
        for (int i = 1; i < 6; ++i) ri = (tb >= a.d[i].off) ? i : ri;
        const float* src = a.d[ri].src;
        ushort* dst = a.d[ri].dst;
        int src_ld = a.d[ri].src_ld, dst_ld = a.d[ri].dst_ld;
        int local = tb - a.d[ri].off;
        int bx = local % a.d[ri].ktiles;
        int by = local / a.d[ri].ktiles;
        int k0 = bx * 64, n0 = by * 64;
        int c4 = (t & 15) * 4;
        int r = t >> 4;
#pragma unroll
        for (int i = 0; i < 4; ++i) {
            int rr = r + i * 16;
            float4 v = *(const float4*)&src[(size_t)(k0 + rr) * src_ld + n0 + c4];
            tile[rr][c4 + 0] = v.x; tile[rr][c4 + 1] = v.y;
            tile[rr][c4 + 2] = v.z; tile[rr][c4 + 3] = v.w;
        }
        __syncthreads();
        int kk8 = (t & 7) * 8;
        int nn = t >> 3;
#pragma unroll
        for (int i = 0; i < 2; ++i) {
            int n = nn + i * 32;
            ushort tmp[8];
#pragma unroll
            for (int j = 0; j < 8; ++j) tmp[j] = f2bf(tile[kk8 + j][n]);
            *(uint4*)&dst[(size_t)(n0 + n) * dst_ld + k0 + kk8] = *(uint4*)tmp;
        }
    } else {
        int idx = (bid - 15120) * 256 + t;  // 0..4095
        int g = idx >> 10, n = idx & 1023;
        const float* s = (g == 0) ? bi : (g == 1) ? bf_ : (g == 2) ? bc : bo;
        Biasf[idx] = s[n];
    }
}

// ---------------- GEMM1: 256x256 tile, BK=64, 8 waves, deep-pipelined ----------------
// Per K-tile: 4 phases in order (QM,QN) = (0,0),(0,1),(1,0),(1,1).
// Fragment persistence: afr[][] holds current QM's A frags (loaded P1,P3);
// bfr[qn][][] holds BOTH B halves (loaded P1,P2; reused P3,P4).
// -> 24 ds_read_b128 per K-tile per wave (phase distribution 12/4/8/0).
// Stage schedule (quarter-tile freeing, hazard-checked under new phase order):
//   P1: stage A-part1(t+1) -> buf (t+1)&1   (A-part1 of cur read only in P3 of cur tile,
//                                            staged by prev tile's P1, drained at boundary)
//   P2: stage B-part1(t+1) -> buf (t+1)&1
//   P3: stage A-part0(t+2) -> buf t&1       (A-part0 last read in P1; all waves past P2 barrier)
//   P4: stage B-part0(t+2) -> buf t&1       (B-part0 last read in P1 -- persisted, not re-read)
// Boundary wait once per tile: vmcnt(4) keeps this tile's P3/P4 stages in flight.
// A LDS: identity rows [0..255]; part0={0-63,128-191}, part1={64-127,192-255}.
// B LDS: permuted rows, LDS row (qn*128 + wc*32 + jj*16 + l16) holds global col
//        n0 + wc*64 + qn*32 + jj*16 + l16. Both sides keep the kg^(row&7) swizzle.
__global__ __launch_bounds__(512) void k_gemm1(const ushort* __restrict__ xhcb,
                                               const ushort* __restrict__ WT,
                                               const float* __restrict__ bias,
                                               ushort* __restrict__ Pre) {
    __shared__ __align__(16) ushort lds[2][32768];  // per buf: A 16384, B 16384 (128 KiB)
    const int t = threadIdx.x;
    const int m0 = blockIdx.x * 256;
    const int by = blockIdx.y;
    const int n0 = by * 256;
    const int KTOT = (by < 8) ? 3072 : 2048;
    const int NT = KTOT >> 6;
    const int w = t >> 6, l = t & 63;
    const int wr = w >> 2, wc = w & 3;  // 2 (M) x 4 (N) waves
    const int lane16 = l & 15, quad = l >> 4;
    const int r7 = lane16 & 7;
    const int rowt = t >> 3;            // 0..63 staging row within 64-row round
    const int kg = (t & 7) ^ (rowt & 7);  // swizzled source 16B k-group
    const int brow_hi = rowt >> 5, brow_lo = rowt & 31;
    f32x4 acc[8][4] = {};
    bfrag afr[4][2];      // current QM's A fragments
    bfrag bfr[2][2][2];   // [qn][jj][h] -- both B halves persist across the K-tile

    const ushort* Ag = xhcb + (size_t)(m0 + rowt) * 3072 + kg * 8;
    const ushort* Bg = WT + (size_t)(n0 + brow_lo) * 3072 + kg * 8;

#define STAGE_A(BUF, PI, KT)                                                       \
    do {                                                                           \
        GLDS16(Ag + (size_t)((PI) * 64) * 3072 + (KT) * 64,                        \
               &lds[BUF][((PI) * 64) * 64] + t * 8);                               \
        GLDS16(Ag + (size_t)((PI) * 64 + 128) * 3072 + (KT) * 64,                  \
               &lds[BUF][((PI) * 64 + 128) * 64] + t * 8);                         \
    } while (0)

#define STAGE_B(BUF, PI, KT)                                                       \
    do {                                                                           \
        GLDS16(Bg + (size_t)((PI) * 32 + brow_hi * 64) * 3072 + (KT) * 64,         \
               &lds[BUF][16384 + ((PI) * 128) * 64] + t * 8);                      \
        GLDS16(Bg + (size_t)((PI) * 32 + (2 + brow_hi) * 64) * 3072 + (KT) * 64,   \
               &lds[BUF][16384 + ((PI) * 128 + 64) * 64] + t * 8);                 \
    } while (0)

#define LDA(QM)                                                                           \
    do {                                                                                  \
        _Pragma("unroll") for (int ii = 0; ii < 4; ++ii) {                                \
            _Pragma("unroll") for (int h = 0; h < 2; ++h)                                 \
                afr[ii][h] = *(const bfrag*)&Acur[(wr * 128 + (QM) * 64 + ii * 16 + lane16) * 64 + \
                                                  (((h * 4 + quad) ^ r7) * 8)];           \
        }                                                                                 \
    } while (0)

#define LDB(QN)                                                                           \
    do {                                                                                  \
        _Pragma("unroll") for (int jj = 0; jj < 2; ++jj) {                                \
            _Pragma("unroll") for (int h = 0; h < 2; ++h)                                 \
                bfr[QN][jj][h] = *(const bfrag*)&Bcur[((QN) * 128 + wc * 32 + jj * 16 + lane16) * 64 + \
                                                      (((h * 4 + quad) ^ r7) * 8)];       \
        }                                                                                 \
    } while (0)

#define MM(QM, QN)                                                                        \
    do {                                                                                  \
        __builtin_amdgcn_s_setprio(1);                                                    \
        _Pragma("unroll") for (int ii = 0; ii < 4; ++ii) {                                \
            _Pragma("unroll") for (int jj = 0; jj < 2; ++jj) {                            \
                _Pragma("unroll") for (int h = 0; h < 2; ++h)                             \
                    acc[(QM) * 4 + ii][(QN) * 2 + jj] =                                   \
                        __builtin_amdgcn_mfma_f32_16x16x32_bf16(                          \
                            afr[ii][h], bfr[QN][jj][h], acc[(QM) * 4 + ii][(QN) * 2 + jj],\
                            0, 0, 0);                                                     \
            }                                                                             \
        }                                                                                 \
        __builtin_amdgcn_s_setprio(0);                                                    \
    } while (0)

#define BAR_WAIT()                                              \
    do {                                                        \
        __builtin_amdgcn_s_barrier();                           \
        asm volatile("s_waitcnt lgkmcnt(0)" ::: "memory");      \
    } while (0)

    // prologue: tile0 complete + tile1 part0s; tile0's 8 loads must land -> vmcnt(4)
    STAGE_A(0, 0, 0); STAGE_B(0, 0, 0);
    STAGE_A(0, 1, 0); STAGE_B(0, 1, 0);
    STAGE_A(1, 0, 1); STAGE_B(1, 0, 1);
    asm volatile("s_waitcnt vmcnt(4)" ::: "memory");
    __builtin_amdgcn_s_barrier();

    for (int kt = 0; kt < NT; ++kt) {
        const int cur = kt & 1;
        const int nxt = cur ^ 1;
        const ushort* Acur = &lds[cur][0];
        const ushort* Bcur = Acur + 16384;
        // P1 (0,0): load afr(qm=0) + bfr[0]; stage A-part1(t+1)
        LDA(0); LDB(0);
        if (kt + 1 < NT) STAGE_A(nxt, 1, kt + 1);
        BAR_WAIT();
        MM(0, 0);
        __builtin_amdgcn_s_barrier();
        // P2 (0,1): load bfr[1]; stage B-part1(t+1)
        LDB(1);
        if (kt + 1 < NT) STAGE_B(nxt, 1, kt + 1);
        BAR_WAIT();
        MM(0, 1);
        __builtin_amdgcn_s_barrier();
        // P3 (1,0): load afr(qm=1); reuse bfr[0]; stage A-part0(t+2)
        LDA(1);
        if (kt + 2 < NT) STAGE_A(cur, 0, kt + 2);
        BAR_WAIT();
        MM(1, 0);
        __builtin_amdgcn_s_barrier();
        // P4 (1,1): no ds loads; reuse afr + bfr[1]; stage B-part0(t+2)
        if (kt + 2 < NT) STAGE_B(cur, 0, kt + 2);
        BAR_WAIT();
        MM(1, 1);
        if (kt + 2 < NT) {
            asm volatile("s_waitcnt vmcnt(4)" ::: "memory");
        } else if (kt + 1 < NT) {
            asm volatile("s_waitcnt vmcnt(0)" ::: "memory");
        }
        __builtin_amdgcn_s_barrier();
    }
#undef BAR_WAIT
#undef MM
#undef LDB
#undef LDA
#undef STAGE_B
#undef STAGE_A

#pragma unroll
    for (int i = 0; i < 8; ++i) {
#pragma unroll
        for (int jj = 0; jj < 4; ++jj) {
            int col = n0 + wc * 64 + (jj >> 1) * 32 + (jj & 1) * 16 + lane16;
            float bv = bias[col];
            int rbase = m0 + wr * 128 + i * 16 + quad * 4;
#pragma unroll
            for (int r = 0; r < 4; ++r)
                Pre[(size_t)(rbase + r) * 4096 + col] = f2bf(acc[i][jj][r] + bv);
        }
    }
}

// ---------------- c_new = sigmoid(f)*c + sigmoid(i)*tanh(cand) ----------------
__global__ __launch_bounds__(256) void k_cnew(const ushort* __restrict__ Pre,
                                              const float* __restrict__ cin,
                                              ushort* __restrict__ Cnewb,
                                              float* __restrict__ out) {
    int idx8 = blockIdx.x * 256 + threadIdx.x;  // 1,048,576 total
    int b = idx8 >> 7;
    int n8 = (idx8 & 127) * 8;
    uint4 vi = *(const uint4*)(Pre + (size_t)b * 4096 + n8);
    uint4 vf = *(const uint4*)(Pre + (size_t)b * 4096 + 1024 + n8);
    uint4 vc = *(const uint4*)(Pre + (size_t)b * 4096 + 2048 + n8);
    float4 c0 = *(const float4*)(cin + (size_t)b * 1024 + n8);
    float4 c1 = *(const float4*)(cin + (size_t)b * 1024 + n8 + 4);
    const ushort* pi = (const ushort*)&vi;
    const ushort* pf = (const ushort*)&vf;
    const ushort* pc = (const ushort*)&vc;
    float cv[8] = {c0.x, c0.y, c0.z, c0.w, c1.x, c1.y, c1.z, c1.w};
    float cn[8];
    ushort cb[8];
#pragma unroll
    for (int j = 0; j < 8; ++j) {
        float iv = sigmoidf_(bf2f(pi[j]));
        float fv = sigmoidf_(bf2f(pf[j]));
        float cp = tanhf(bf2f(pc[j]));
        cn[j] = fv * cv[j] + iv * cp;
        cb[j] = f2bf(cn[j]);
    }
    *(uint4*)(Cnewb + (size_t)b * 1024 + n8) = *(uint4*)cb;
    float* orow = out + (size_t)b * 2050 + 1024 + n8;  // 8B-aligned
#pragma unroll
    for (int j = 0; j < 4; ++j)
        *(float2*)(orow + j * 2) = make_float2(cn[j * 2], cn[j * 2 + 1]);
}

// ---------------- GEMM2: o_pre = Pre_o + c_new @ W_o[2048:]; h_new = sig(o)*tanh(c_new)
__global__ __launch_bounds__(256) void k_gemm2(const ushort* __restrict__ Cnewb,
                                               const ushort* __restrict__ WoCT,
                                               const ushort* __restrict__ Pre,
                                               ushort* __restrict__ Hnewb,
                                               float* __restrict__ out) {
    __shared__ __align__(16) ushort As[128 * 64];
    __shared__ __align__(16) ushort Bs[128 * 64];
    int t = threadIdx.x;
    int m0 = blockIdx.x * 128, n0 = blockIdx.y * 128;
    int w = t >> 6, l = t & 63;
    int wm = (w & 1) * 64, wn = (w >> 1) * 64;
    int lane16 = l & 15, quad = l >> 4;
    int rowt = t >> 3;
    int kg = (t & 7) ^ (rowt & 7);
    int r7 = lane16 & 7;
    f32x4 acc[4][4] = {};

    const ushort* Abase = Cnewb + (size_t)(m0 + rowt) * 1024 + kg * 8;
    const ushort* Bbase = WoCT + (size_t)(n0 + rowt) * 1024 + kg * 8;

    for (int k0 = 0; k0 < 1024; k0 += 64) {
#pragma unroll
        for (int q = 0; q < 4; ++q)
            GLDS16(Abase + (size_t)q * 32 * 1024 + k0, As + q * 2048 + t * 8);
#pragma unroll
        for (int q = 0; q < 4; ++q)
            GLDS16(Bbase + (size_t)q * 32 * 1024 + k0, Bs + q * 2048 + t * 8);
        __syncthreads();
#pragma unroll
        for (int hh = 0; hh < 2; ++hh) {
            int slot8 = ((hh * 4 + quad) ^ r7) * 8;
            bfrag af[4], bfr[4];
#pragma unroll
            for (int i = 0; i < 4; ++i) {
                af[i]  = *(const bfrag*)&As[(wm + i * 16 + lane16) * 64 + slot8];
                bfr[i] = *(const bfrag*)&Bs[(wn + i * 16 + lane16) * 64 + slot8];
            }
#pragma unroll
            for (int i = 0; i < 4; ++i)
#pragma unroll
                for (int j = 0; j < 4; ++j)
                    acc[i][j] = __builtin_amdgcn_mfma_f32_16x16x32_bf16(af[i], bfr[j], acc[i][j], 0, 0, 0);
        }
        __syncthreads();
    }
#pragma unroll
    for (int i = 0; i < 4; ++i) {
#pragma unroll
        for (int j = 0; j < 4; ++j) {
            int col = n0 + wn + j * 16 + lane16;
            int rbase = m0 + wm + i * 16 + quad * 4;
#pragma unroll
            for (int r = 0; r < 4; ++r) {
                int row = rbase + r;
                float opre = acc[i][j][r] + bf2f(Pre[(size_t)row * 4096 + 3072 + col]);
                float o = sigmoidf_(opre);
                float cnv = bf2f(Cnewb[(size_t)row * 1024 + col]);
                float hv = o * tanhf(cnv);
                Hnewb[(size_t)row * 1024 + col] = f2bf(hv);
                out[(size_t)row * 2050 + col] = hv;
            }
        }
    }
}

// ---------------- attention + gumbel + alpha/beta (16 rows per block) ----------------
__global__ __launch_bounds__(256) void k_attn(
    const ushort* __restrict__ Hnewb, const float* __restrict__ outr,
    const float* __restrict__ x, const float* __restrict__ memory,
    const float* __restrict__ u_gs, const float* __restrict__ u_a,
    const float* __restrict__ u_b, const ushort* __restrict__ WmT,
    const float* __restrict__ b_m,
    const float* __restrict__ w_a_h, const float* __restrict__ w_a_x,
    const float* __restrict__ w_a_r, const float* __restrict__ w_b_h,
    const float* __restrict__ w_b_x, const float* __restrict__ w_b_r,
    float* __restrict__ out) {
    __shared__ float sMicro[16 * 64];
    __shared__ float sAttn[16 * 16];
    __shared__ float sSamp[16 * 64];

    int b0 = blockIdx.x * 16;
    int t = threadIdx.x;
    int w = t >> 6, l = t & 63;
    int lane16 = l & 15, quad = l >> 4;

    // wave w computes micro[0:16][16w:16w+16] via MFMA
    {
        f32x4 acc = {0.f, 0.f, 0.f, 0.f};
        const ushort* Ab = Hnewb + (size_t)(b0 + lane16) * 1024 + quad * 8;
        const ushort* Bb = WmT + (size_t)(w * 16 + lane16) * 1024 + quad * 8;
#pragma unroll 4
        for (int k0 = 0; k0 < 1024; k0 += 32) {
            bfrag av = *(const bfrag*)(Ab + k0);
            bfrag bv = *(const bfrag*)(Bb + k0);
            acc = __builtin_amdgcn_mfma_f32_16x16x32_bf16(av, bv, acc, 0, 0, 0);
        }
        float bm = b_m[w * 16 + lane16];
#pragma unroll
        for (int r = 0; r < 4; ++r)
            sMicro[(quad * 4 + r) * 64 + w * 16 + lane16] = acc[r] + bm;
    }
    __syncthreads();

    // logits + gumbel softmax over M=16
    {
        int r = t >> 4, m = t & 15;
        const float4* mem4 = (const float4*)(memory + (size_t)(b0 + r) * 1024 + m * 64);
        float lg = 0.f;
#pragma unroll
        for (int k4 = 0; k4 < 16; ++k4) {
            float4 mv = mem4[k4];
            const float* sm = &sMicro[r * 64 + k4 * 4];
            lg += mv.x * sm[0] + mv.y * sm[1] + mv.z * sm[2] + mv.w * sm[3];
        }
        float u = u_gs[(b0 + r) * 16 + m];
        float z = lg - logf(-logf(u));  // TAU = 1
        float zm = z;
        for (int off = 8; off; off >>= 1) zm = fmaxf(zm, __shfl_xor(zm, off, 16));
        float p = expf(z - zm);
        float ps = p;
        for (int off = 8; off; off >>= 1) ps += __shfl_xor(ps, off, 16);
        sAttn[r * 16 + m] = p / ps;
    }
    __syncthreads();

    // sampled = memory^T @ attn + 1
#pragma unroll
    for (int q = 0; q < 4; ++q) {
        int r = w * 4 + q;
        const float* mem = memory + (size_t)(b0 + r) * 1024 + l;
        float s = 0.f;
#pragma unroll
        for (int m = 0; m < 16; ++m) s += sAttn[r * 16 + m] * mem[m * 64];
        sSamp[r * 64 + l] = s + 1.0f;
    }
    __syncthreads();

    // alpha / beta
    {
        int r = t >> 4, s16 = t & 15;
        size_t hoff = (size_t)(b0 + r) * 2050;
        size_t xoff = (size_t)(b0 + r) * 1024;
        float za = 0.f, zb = 0.f;
        for (int kk = 0; kk < 64; ++kk) {
            int k = s16 + kk * 16;
            float hv = outr[hoff + k];
            float xv = x[xoff + k];
            za += hv * w_a_h[k] + xv * w_a_x[k];
            zb += hv * w_b_h[k] + xv * w_b_x[k];
        }
#pragma unroll
        for (int k = s16 * 4; k < s16 * 4 + 4; ++k) {
            float sv = sSamp[r * 64 + k];
            za += sv * w_a_r[k];
            zb += sv * w_b_r[k];
        }
        for (int off = 8; off; off >>= 1) {
            za += __shfl_xor(za, off, 16);
            zb += __shfl_xor(zb, off, 16);
        }
        if (s16 == 0) {
            float ua = u_a[b0 + r];
            float ub = u_b[b0 + r];
            float la = logf(ua) - log1pf(-ua);
            float lb = logf(ub) - log1pf(-ub);
            out[(size_t)(b0 + r) * 2050 + 2048] = sigmoidf_(za + la);
            out[(size_t)(b0 + r) * 2050 + 2049] = sigmoidf_(zb + lb);
        }
    }
}

extern "C" void kernel_launch(void* const* d_in, const int* in_sizes, int n_in,
                              void* d_out, int out_size, void* d_ws, size_t ws_size,
                              hipStream_t stream) {
    const float* x      = (const float*)d_in[0];
    const float* h      = (const float*)d_in[1];
    const float* c      = (const float*)d_in[2];
    const float* memory = (const float*)d_in[3];
    const float* u_gs   = (const float*)d_in[4];
    const float* u_a    = (const float*)d_in[5];
    const float* u_b    = (const float*)d_in[6];
    const float* W_i    = (const float*)d_in[7];
    const float* b_i    = (const float*)d_in[8];
    const float* W_f    = (const float*)d_in[9];
    const float* b_f    = (const float*)d_in[10];
    const float* W_o    = (const float*)d_in[11];
    const float* b_o    = (const float*)d_in[12];
    const float* W_cand = (const float*)d_in[13];
    const float* b_cand = (const float*)d_in[14];
    const float* W_m    = (const float*)d_in[15];
    const float* b_m    = (const float*)d_in[16];
    const float* w_a_h  = (const float*)d_in[17];
    const float* w_a_x  = (const float*)d_in[18];
    const float* w_a_r  = (const float*)d_in[19];
    const float* w_b_h  = (const float*)d_in[20];
    const float* w_b_x  = (const float*)d_in[21];
    const float* w_b_r  = (const float*)d_in[22];
    float* out = (float*)d_out;

    // workspace carve (bytes)
    char* ws = (char*)d_ws;
    ushort* WT    = (ushort*)(ws);                 // 25,165,824
    ushort* WoCT  = (ushort*)(ws + 25165824);      //  2,097,152
    ushort* Pre   = (ushort*)(ws + 27262976);      // 67,108,864
    ushort* xhcb  = (ushort*)(ws + 94371840);      // 50,331,648
    float*  Biasf = (float*)(ws + 144703488);      //     16,384
    ushort* WmT   = (ushort*)(ws + 144719872);     //    131,072
    ushort* Cnewb = xhcb;                          // alias: xhcb dead after gemm1
    ushort* Hnewb = WT;                            // alias: WT dead after gemm1

    TA ta;
    ta.d[0] = {W_i,                       WT,                        1024, 3072, 48, 0};
    ta.d[1] = {W_f,                       WT + (size_t)1024 * 3072,  1024, 3072, 48, 768};
    ta.d[2] = {W_cand,                    WT + (size_t)2048 * 3072,  1024, 3072, 32, 1536};
    ta.d[3] = {W_o,                       WT + (size_t)3072 * 3072,  1024, 3072, 32, 2048};  // first 2048 rows used
    ta.d[4] = {W_o + (size_t)2048 * 1024, WoCT,                      1024, 1024, 16, 2560};
    ta.d[5] = {W_m,                       WmT,                         64, 1024, 16, 2816};  // 16 blocks only

    k_prep<<<15136, 256, 0, stream>>>(x, h, c, xhcb, ta, b_i, b_f, b_cand, b_o, Biasf);

    // fused gemm1: by<8 -> K=3072 (i,f gates), by>=8 -> K=2048 (cand, o-partial)
    k_gemm1<<<dim3(32, 16), 512, 0, stream>>>(xhcb, WT, Biasf, Pre);
    k_cnew<<<4096, 256, 0, stream>>>(Pre, c, Cnewb, out);
    k_gemm2<<<dim3(64, 8), 256, 0, stream>>>(Cnewb, WoCT, Pre, Hnewb, out);
    k_attn<<<512, 256, 0, stream>>>(Hnewb, out, x, memory, u_gs, u_a, u_b, WmT, b_m,
                                    w_a_h, w_a_x, w_a_r, w_b_h, w_b_x, w_b_r, out);
}

// Round 3
// 476.217 us; speedup vs baseline: 1.0966x; 1.0072x over previous
//
#include <hip/hip_runtime.h>

typedef __bf16 bfrag __attribute__((ext_vector_type(8)));
typedef float f32x4 __attribute__((ext_vector_type(4)));

#define GLDS16(g, l) __builtin_amdgcn_global_load_lds( \
    (__attribute__((address_space(1))) void*)(g),      \
    (__attribute__((address_space(3))) void*)(l), 16, 0, 0)

__device__ __forceinline__ float bf2f(ushort u) {
    return __uint_as_float(((unsigned)u) << 16);
}
__device__ __forceinline__ ushort f2bf(float f) {
    unsigned u = __float_as_uint(f);
    u += 0x7fff + ((u >> 16) & 1);
    return (ushort)(u >> 16);
}
__device__ __forceinline__ float sigmoidf_(float v) {
    return 1.0f / (1.0f + expf(-v));
}

// ---------------- merged prep: castcat + all transposes + bias concat ----------------
struct TD { const float* src; ushort* dst; int src_ld; int dst_ld; int ktiles; int off; };
struct TA { TD d[6]; };

__global__ __launch_bounds__(256) void k_prep(const float* __restrict__ x,
                                              const float* __restrict__ h,
                                              const float* __restrict__ c,
                                              ushort* __restrict__ xhcb, TA a,
                                              const float* __restrict__ bi,
                                              const float* __restrict__ bf_,
                                              const float* __restrict__ bc,
                                              const float* __restrict__ bo,
                                              float* __restrict__ Biasf) {
    __shared__ float tile[64][65];
    int bid = blockIdx.x;
    int t = threadIdx.x;
    if (bid < 12288) {
        // castcat: xhcb[b][0:3072] = bf16([x|h|c][b]), 8 elems/thread
        int idx = bid * 256 + t;
        int row = idx / 384;
        int c8 = (idx - row * 384) * 8;
        const float* s = (c8 < 1024) ? &x[(size_t)row * 1024 + c8]
                       : (c8 < 2048) ? &h[(size_t)row * 1024 + (c8 - 1024)]
                                     : &c[(size_t)row * 1024 + (c8 - 2048)];
        float4 va = *(const float4*)s;
        float4 vb = *(const float4*)(s + 4);
        ushort tmp[8] = {f2bf(va.x), f2bf(va.y), f2bf(va.z), f2bf(va.w),
                         f2bf(vb.x), f2bf(vb.y), f2bf(vb.z), f2bf(vb.w)};
        *(uint4*)&xhcb[(size_t)idx * 8] = *(uint4*)tmp;
    } else if (bid < 15120) {
        // transpose+cast: dst[n*dst_ld + k] = bf16(src[k*src_ld + n])
        int tb = bid - 12288;
        int ri = 0;
#pragma unroll
        for (int i = 1; i < 6; ++i) ri = (tb >= a.d[i].off) ? i : ri;
        const float* src = a.d[ri].src;
        ushort* dst = a.d[ri].dst;
        int src_ld = a.d[ri].src_ld, dst_ld = a.d[ri].dst_ld;
        int local = tb - a.d[ri].off;
        int bx = local % a.d[ri].ktiles;
        int by = local / a.d[ri].ktiles;
        int k0 = bx * 64, n0 = by * 64;
        int c4 = (t & 15) * 4;
        int r = t >> 4;
#pragma unroll
        for (int i = 0; i < 4; ++i) {
            int rr = r + i * 16;
            float4 v = *(const float4*)&src[(size_t)(k0 + rr) * src_ld + n0 + c4];
            tile[rr][c4 + 0] = v.x; tile[rr][c4 + 1] = v.y;
            tile[rr][c4 + 2] = v.z; tile[rr][c4 + 3] = v.w;
        }
        __syncthreads();
        int kk8 = (t & 7) * 8;
        int nn = t >> 3;
#pragma unroll
        for (int i = 0; i < 2; ++i) {
            int n = nn + i * 32;
            ushort tmp[8];
#pragma unroll
            for (int j = 0; j < 8; ++j) tmp[j] = f2bf(tile[kk8 + j][n]);
            *(uint4*)&dst[(size_t)(n0 + n) * dst_ld + k0 + kk8] = *(uint4*)tmp;
        }
    } else {
        int idx = (bid - 15120) * 256 + t;  // 0..4095
        int g = idx >> 10, n = idx & 1023;
        const float* s = (g == 0) ? bi : (g == 1) ? bf_ : (g == 2) ? bc : bo;
        Biasf[idx] = s[n];
    }
}

// ---------------- GEMM1: 256x256 tile, BK=64, 8 waves, deep-pipelined (v2) ----------------
// h-split phases: P1=(QM0,h0) P2=(QM0,h1) P3=(QM1,h0) P4=(QM1,h1); each phase's MFMA
// covers all 4 N-subtiles (16 MFMA). Reads per phase: 8/8/4/4 (B halves read once,
// reused at P3/P4). Reads for phase p+1 are issued in window p (P1 issues P1+P2's)
// so they fly under the preceding MFMA; compiler inserts per-register lgkmcnt waits.
// ONE barrier per phase. Validity: a stage issued in window p lands while only
// reads of windows p..p+1 can be in flight (all older reads completed before their
// MFMA, which precedes the barrier the staging wave passed). Mapping:
//   P1: stage A-part1(t+1)->nxt   (in-flight reads target cur only)        OK
//   P2: stage B-part1(t+1)->nxt                                            OK
//   P3: stage A-part0(t+2)->cur   (in-flight: P3/P4 reads = A-part1 only)  OK
//   P4: stage B-part0(t+2)->cur   (in-flight: P4 reads = A-part1 h1 only)  OK
// Boundary: vmcnt(4) once per tile keeps the t+2 stages in flight.
// A LDS: identity rows [0..255]; part0={0-63,128-191}, part1={64-127,192-255}.
// B LDS: permuted rows, LDS row (qn*128 + wc*32 + jj*16 + l16) holds global col
//        n0 + wc*64 + qn*32 + jj*16 + l16. Both sides keep the kg^(row&7) swizzle.
__global__ __launch_bounds__(512) void k_gemm1(const ushort* __restrict__ xhcb,
                                               const ushort* __restrict__ WT,
                                               const float* __restrict__ bias,
                                               ushort* __restrict__ Pre) {
    __shared__ __align__(16) ushort lds[2][32768];  // per buf: A 16384, B 16384 (128 KiB)
    const int t = threadIdx.x;
    const int m0 = blockIdx.x * 256;
    const int by = blockIdx.y;
    const int n0 = by * 256;
    const int KTOT = (by < 8) ? 3072 : 2048;
    const int NT = KTOT >> 6;
    const int w = t >> 6, l = t & 63;
    const int wr = w >> 2, wc = w & 3;  // 2 (M) x 4 (N) waves
    const int lane16 = l & 15, quad = l >> 4;
    const int r7 = lane16 & 7;
    const int rowt = t >> 3;            // 0..63 staging row within 64-row round
    const int kg = (t & 7) ^ (rowt & 7);  // swizzled source 16B k-group
    const int brow_hi = rowt >> 5, brow_lo = rowt & 31;
    f32x4 acc[8][4] = {};

    const ushort* Ag = xhcb + (size_t)(m0 + rowt) * 3072 + kg * 8;
    const ushort* Bg = WT + (size_t)(n0 + brow_lo) * 3072 + kg * 8;

#define STAGE_A(BUF, PI, KT)                                                       \
    do {                                                                           \
        GLDS16(Ag + (size_t)((PI) * 64) * 3072 + (KT) * 64,                        \
               &lds[BUF][((PI) * 64) * 64] + t * 8);                               \
        GLDS16(Ag + (size_t)((PI) * 64 + 128) * 3072 + (KT) * 64,                  \
               &lds[BUF][((PI) * 64 + 128) * 64] + t * 8);                         \
    } while (0)

#define STAGE_B(BUF, PI, KT)                                                       \
    do {                                                                           \
        GLDS16(Bg + (size_t)((PI) * 32 + brow_hi * 64) * 3072 + (KT) * 64,         \
               &lds[BUF][16384 + ((PI) * 128) * 64] + t * 8);                      \
        GLDS16(Bg + (size_t)((PI) * 32 + (2 + brow_hi) * 64) * 3072 + (KT) * 64,   \
               &lds[BUF][16384 + ((PI) * 128 + 64) * 64] + t * 8);                 \
    } while (0)

#define LDAF(dst, QM, H)                                                                  \
    do {                                                                                  \
        _Pragma("unroll") for (int ii = 0; ii < 4; ++ii)                                  \
            dst[ii] = *(const bfrag*)&Acur[(wr * 128 + (QM) * 64 + ii * 16 + lane16) * 64 + \
                                           ((((H) * 4 + quad) ^ r7) * 8)];                \
    } while (0)

#define LDBF(dst, H)                                                                      \
    do {                                                                                  \
        _Pragma("unroll") for (int jj = 0; jj < 4; ++jj)                                  \
            dst[jj] = *(const bfrag*)&Bcur[((jj >> 1) * 128 + wc * 32 + (jj & 1) * 16 + lane16) * 64 + \
                                           ((((H) * 4 + quad) ^ r7) * 8)];                \
    } while (0)

#define MMH(QM, AH, BH)                                                                   \
    do {                                                                                  \
        __builtin_amdgcn_s_setprio(1);                                                    \
        _Pragma("unroll") for (int ii = 0; ii < 4; ++ii) {                                \
            _Pragma("unroll") for (int jj = 0; jj < 4; ++jj)                              \
                acc[(QM) * 4 + ii][jj] = __builtin_amdgcn_mfma_f32_16x16x32_bf16(         \
                    AH[ii], BH[jj], acc[(QM) * 4 + ii][jj], 0, 0, 0);                     \
        }                                                                                 \
        __builtin_amdgcn_s_setprio(0);                                                    \
    } while (0)

    // prologue: tile0 complete + tile1 part0s; tile0's 8 loads must land -> vmcnt(4)
    STAGE_A(0, 0, 0); STAGE_B(0, 0, 0);
    STAGE_A(0, 1, 0); STAGE_B(0, 1, 0);
    STAGE_A(1, 0, 1); STAGE_B(1, 0, 1);
    asm volatile("s_waitcnt vmcnt(4)" ::: "memory");
    __builtin_amdgcn_s_barrier();

    for (int kt = 0; kt < NT; ++kt) {
        const int cur = kt & 1;
        const int nxt = cur ^ 1;
        const ushort* Acur = &lds[cur][0];
        const ushort* Bcur = Acur + 16384;
        bfrag a0h0[4], a0h1[4], a1h0[4], a1h1[4], bh0[4], bh1[4];
        // P1 (QM0,h0): issue P1+P2 reads; stage A-part1(t+1)
        LDAF(a0h0, 0, 0); LDBF(bh0, 0);
        LDAF(a0h1, 0, 1); LDBF(bh1, 1);
        if (kt + 1 < NT) STAGE_A(nxt, 1, kt + 1);
        MMH(0, a0h0, bh0);
        __builtin_amdgcn_s_barrier();
        // P2 (QM0,h1): issue P3 reads; stage B-part1(t+1)
        LDAF(a1h0, 1, 0);
        if (kt + 1 < NT) STAGE_B(nxt, 1, kt + 1);
        MMH(0, a0h1, bh1);
        __builtin_amdgcn_s_barrier();
        // P3 (QM1,h0): issue P4 reads; stage A-part0(t+2)
        LDAF(a1h1, 1, 1);
        if (kt + 2 < NT) STAGE_A(cur, 0, kt + 2);
        MMH(1, a1h0, bh0);
        __builtin_amdgcn_s_barrier();
        // P4 (QM1,h1): stage B-part0(t+2); boundary vmcnt
        if (kt + 2 < NT) STAGE_B(cur, 0, kt + 2);
        MMH(1, a1h1, bh1);
        if (kt + 2 < NT) {
            asm volatile("s_waitcnt vmcnt(4)" ::: "memory");
        } else if (kt + 1 < NT) {
            asm volatile("s_waitcnt vmcnt(0)" ::: "memory");
        }
        __builtin_amdgcn_s_barrier();
    }
#undef MMH
#undef LDBF
#undef LDAF
#undef STAGE_B
#undef STAGE_A

#pragma unroll
    for (int i = 0; i < 8; ++i) {
#pragma unroll
        for (int jj = 0; jj < 4; ++jj) {
            int col = n0 + wc * 64 + (jj >> 1) * 32 + (jj & 1) * 16 + lane16;
            float bv = bias[col];
            int rbase = m0 + wr * 128 + i * 16 + quad * 4;
#pragma unroll
            for (int r = 0; r < 4; ++r)
                Pre[(size_t)(rbase + r) * 4096 + col] = f2bf(acc[i][jj][r] + bv);
        }
    }
}

// ---------------- c_new = sigmoid(f)*c + sigmoid(i)*tanh(cand) ----------------
__global__ __launch_bounds__(256) void k_cnew(const ushort* __restrict__ Pre,
                                              const float* __restrict__ cin,
                                              ushort* __restrict__ Cnewb,
                                              float* __restrict__ out) {
    int idx8 = blockIdx.x * 256 + threadIdx.x;  // 1,048,576 total
    int b = idx8 >> 7;
    int n8 = (idx8 & 127) * 8;
    uint4 vi = *(const uint4*)(Pre + (size_t)b * 4096 + n8);
    uint4 vf = *(const uint4*)(Pre + (size_t)b * 4096 + 1024 + n8);
    uint4 vc = *(const uint4*)(Pre + (size_t)b * 4096 + 2048 + n8);
    float4 c0 = *(const float4*)(cin + (size_t)b * 1024 + n8);
    float4 c1 = *(const float4*)(cin + (size_t)b * 1024 + n8 + 4);
    const ushort* pi = (const ushort*)&vi;
    const ushort* pf = (const ushort*)&vf;
    const ushort* pc = (const ushort*)&vc;
    float cv[8] = {c0.x, c0.y, c0.z, c0.w, c1.x, c1.y, c1.z, c1.w};
    float cn[8];
    ushort cb[8];
#pragma unroll
    for (int j = 0; j < 8; ++j) {
        float iv = sigmoidf_(bf2f(pi[j]));
        float fv = sigmoidf_(bf2f(pf[j]));
        float cp = tanhf(bf2f(pc[j]));
        cn[j] = fv * cv[j] + iv * cp;
        cb[j] = f2bf(cn[j]);
    }
    *(uint4*)(Cnewb + (size_t)b * 1024 + n8) = *(uint4*)cb;
    float* orow = out + (size_t)b * 2050 + 1024 + n8;  // 8B-aligned
#pragma unroll
    for (int j = 0; j < 4; ++j)
        *(float2*)(orow + j * 2) = make_float2(cn[j * 2], cn[j * 2 + 1]);
}

// ---------------- GEMM2: o_pre = Pre_o + c_new @ W_o[2048:]; h_new = sig(o)*tanh(c_new)
__global__ __launch_bounds__(256) void k_gemm2(const ushort* __restrict__ Cnewb,
                                               const ushort* __restrict__ WoCT,
                                               const ushort* __restrict__ Pre,
                                               ushort* __restrict__ Hnewb,
                                               float* __restrict__ out) {
    __shared__ __align__(16) ushort As[128 * 64];
    __shared__ __align__(16) ushort Bs[128 * 64];
    int t = threadIdx.x;
    int m0 = blockIdx.x * 128, n0 = blockIdx.y * 128;
    int w = t >> 6, l = t & 63;
    int wm = (w & 1) * 64, wn = (w >> 1) * 64;
    int lane16 = l & 15, quad = l >> 4;
    int rowt = t >> 3;
    int kg = (t & 7) ^ (rowt & 7);
    int r7 = lane16 & 7;
    f32x4 acc[4][4] = {};

    const ushort* Abase = Cnewb + (size_t)(m0 + rowt) * 1024 + kg * 8;
    const ushort* Bbase = WoCT + (size_t)(n0 + rowt) * 1024 + kg * 8;

    for (int k0 = 0; k0 < 1024; k0 += 64) {
#pragma unroll
        for (int q = 0; q < 4; ++q)
            GLDS16(Abase + (size_t)q * 32 * 1024 + k0, As + q * 2048 + t * 8);
#pragma unroll
        for (int q = 0; q < 4; ++q)
            GLDS16(Bbase + (size_t)q * 32 * 1024 + k0, Bs + q * 2048 + t * 8);
        __syncthreads();
#pragma unroll
        for (int hh = 0; hh < 2; ++hh) {
            int slot8 = ((hh * 4 + quad) ^ r7) * 8;
            bfrag af[4], bfr[4];
#pragma unroll
            for (int i = 0; i < 4; ++i) {
                af[i]  = *(const bfrag*)&As[(wm + i * 16 + lane16) * 64 + slot8];
                bfr[i] = *(const bfrag*)&Bs[(wn + i * 16 + lane16) * 64 + slot8];
            }
#pragma unroll
            for (int i = 0; i < 4; ++i)
#pragma unroll
                for (int j = 0; j < 4; ++j)
                    acc[i][j] = __builtin_amdgcn_mfma_f32_16x16x32_bf16(af[i], bfr[j], acc[i][j], 0, 0, 0);
        }
        __syncthreads();
    }
#pragma unroll
    for (int i = 0; i < 4; ++i) {
#pragma unroll
        for (int j = 0; j < 4; ++j) {
            int col = n0 + wn + j * 16 + lane16;
            int rbase = m0 + wm + i * 16 + quad * 4;
#pragma unroll
            for (int r = 0; r < 4; ++r) {
                int row = rbase + r;
                float opre = acc[i][j][r] + bf2f(Pre[(size_t)row * 4096 + 3072 + col]);
                float o = sigmoidf_(opre);
                float cnv = bf2f(Cnewb[(size_t)row * 1024 + col]);
                float hv = o * tanhf(cnv);
                Hnewb[(size_t)row * 1024 + col] = f2bf(hv);
                out[(size_t)row * 2050 + col] = hv;
            }
        }
    }
}

// ---------------- attention + gumbel + alpha/beta (16 rows per block) ----------------
__global__ __launch_bounds__(256) void k_attn(
    const ushort* __restrict__ Hnewb, const float* __restrict__ outr,
    const float* __restrict__ x, const float* __restrict__ memory,
    const float* __restrict__ u_gs, const float* __restrict__ u_a,
    const float* __restrict__ u_b, const ushort* __restrict__ WmT,
    const float* __restrict__ b_m,
    const float* __restrict__ w_a_h, const float* __restrict__ w_a_x,
    const float* __restrict__ w_a_r, const float* __restrict__ w_b_h,
    const float* __restrict__ w_b_x, const float* __restrict__ w_b_r,
    float* __restrict__ out) {
    __shared__ float sMicro[16 * 64];
    __shared__ float sAttn[16 * 16];
    __shared__ float sSamp[16 * 64];

    int b0 = blockIdx.x * 16;
    int t = threadIdx.x;
    int w = t >> 6, l = t & 63;
    int lane16 = l & 15, quad = l >> 4;

    // wave w computes micro[0:16][16w:16w+16] via MFMA
    {
        f32x4 acc = {0.f, 0.f, 0.f, 0.f};
        const ushort* Ab = Hnewb + (size_t)(b0 + lane16) * 1024 + quad * 8;
        const ushort* Bb = WmT + (size_t)(w * 16 + lane16) * 1024 + quad * 8;
#pragma unroll 4
        for (int k0 = 0; k0 < 1024; k0 += 32) {
            bfrag av = *(const bfrag*)(Ab + k0);
            bfrag bv = *(const bfrag*)(Bb + k0);
            acc = __builtin_amdgcn_mfma_f32_16x16x32_bf16(av, bv, acc, 0, 0, 0);
        }
        float bm = b_m[w * 16 + lane16];
#pragma unroll
        for (int r = 0; r < 4; ++r)
            sMicro[(quad * 4 + r) * 64 + w * 16 + lane16] = acc[r] + bm;
    }
    __syncthreads();

    // logits + gumbel softmax over M=16
    {
        int r = t >> 4, m = t & 15;
        const float4* mem4 = (const float4*)(memory + (size_t)(b0 + r) * 1024 + m * 64);
        float lg = 0.f;
#pragma unroll
        for (int k4 = 0; k4 < 16; ++k4) {
            float4 mv = mem4[k4];
            const float* sm = &sMicro[r * 64 + k4 * 4];
            lg += mv.x * sm[0] + mv.y * sm[1] + mv.z * sm[2] + mv.w * sm[3];
        }
        float u = u_gs[(b0 + r) * 16 + m];
        float z = lg - logf(-logf(u));  // TAU = 1
        float zm = z;
        for (int off = 8; off; off >>= 1) zm = fmaxf(zm, __shfl_xor(zm, off, 16));
        float p = expf(z - zm);
        float ps = p;
        for (int off = 8; off; off >>= 1) ps += __shfl_xor(ps, off, 16);
        sAttn[r * 16 + m] = p / ps;
    }
    __syncthreads();

    // sampled = memory^T @ attn + 1
#pragma unroll
    for (int q = 0; q < 4; ++q) {
        int r = w * 4 + q;
        const float* mem = memory + (size_t)(b0 + r) * 1024 + l;
        float s = 0.f;
#pragma unroll
        for (int m = 0; m < 16; ++m) s += sAttn[r * 16 + m] * mem[m * 64];
        sSamp[r * 64 + l] = s + 1.0f;
    }
    __syncthreads();

    // alpha / beta
    {
        int r = t >> 4, s16 = t & 15;
        size_t hoff = (size_t)(b0 + r) * 2050;
        size_t xoff = (size_t)(b0 + r) * 1024;
        float za = 0.f, zb = 0.f;
        for (int kk = 0; kk < 64; ++kk) {
            int k = s16 + kk * 16;
            float hv = outr[hoff + k];
            float xv = x[xoff + k];
            za += hv * w_a_h[k] + xv * w_a_x[k];
            zb += hv * w_b_h[k] + xv * w_b_x[k];
        }
#pragma unroll
        for (int k = s16 * 4; k < s16 * 4 + 4; ++k) {
            float sv = sSamp[r * 64 + k];
            za += sv * w_a_r[k];
            zb += sv * w_b_r[k];
        }
        for (int off = 8; off; off >>= 1) {
            za += __shfl_xor(za, off, 16);
            zb += __shfl_xor(zb, off, 16);
        }
        if (s16 == 0) {
            float ua = u_a[b0 + r];
            float ub = u_b[b0 + r];
            float la = logf(ua) - log1pf(-ua);
            float lb = logf(ub) - log1pf(-ub);
            out[(size_t)(b0 + r) * 2050 + 2048] = sigmoidf_(za + la);
            out[(size_t)(b0 + r) * 2050 + 2049] = sigmoidf_(zb + lb);
        }
    }
}

extern "C" void kernel_launch(void* const* d_in, const int* in_sizes, int n_in,
                              void* d_out, int out_size, void* d_ws, size_t ws_size,
                              hipStream_t stream) {
    const float* x      = (const float*)d_in[0];
    const float* h      = (const float*)d_in[1];
    const float* c      = (const float*)d_in[2];
    const float* memory = (const float*)d_in[3];
    const float* u_gs   = (const float*)d_in[4];
    const float* u_a    = (const float*)d_in[5];
    const float* u_b    = (const float*)d_in[6];
    const float* W_i    = (const float*)d_in[7];
    const float* b_i    = (const float*)d_in[8];
    const float* W_f    = (const float*)d_in[9];
    const float* b_f    = (const float*)d_in[10];
    const float* W_o    = (const float*)d_in[11];
    const float* b_o    = (const float*)d_in[12];
    const float* W_cand = (const float*)d_in[13];
    const float* b_cand = (const float*)d_in[14];
    const float* W_m    = (const float*)d_in[15];
    const float* b_m    = (const float*)d_in[16];
    const float* w_a_h  = (const float*)d_in[17];
    const float* w_a_x  = (const float*)d_in[18];
    const float* w_a_r  = (const float*)d_in[19];
    const float* w_b_h  = (const float*)d_in[20];
    const float* w_b_x  = (const float*)d_in[21];
    const float* w_b_r  = (const float*)d_in[22];
    float* out = (float*)d_out;

    // workspace carve (bytes)
    char* ws = (char*)d_ws;
    ushort* WT    = (ushort*)(ws);                 // 25,165,824
    ushort* WoCT  = (ushort*)(ws + 25165824);      //  2,097,152
    ushort* Pre   = (ushort*)(ws + 27262976);      // 67,108,864
    ushort* xhcb  = (ushort*)(ws + 94371840);      // 50,331,648
    float*  Biasf = (float*)(ws + 144703488);      //     16,384
    ushort* WmT   = (ushort*)(ws + 144719872);     //    131,072
    ushort* Cnewb = xhcb;                          // alias: xhcb dead after gemm1
    ushort* Hnewb = WT;                            // alias: WT dead after gemm1

    TA ta;
    ta.d[0] = {W_i,                       WT,                        1024, 3072, 48, 0};
    ta.d[1] = {W_f,                       WT + (size_t)1024 * 3072,  1024, 3072, 48, 768};
    ta.d[2] = {W_cand,                    WT + (size_t)2048 * 3072,  1024, 3072, 32, 1536};
    ta.d[3] = {W_o,                       WT + (size_t)3072 * 3072,  1024, 3072, 32, 2048};  // first 2048 rows used
    ta.d[4] = {W_o + (size_t)2048 * 1024, WoCT,                      1024, 1024, 16, 2560};
    ta.d[5] = {W_m,                       WmT,                         64, 1024, 16, 2816};  // 16 blocks only

    k_prep<<<15136, 256, 0, stream>>>(x, h, c, xhcb, ta, b_i, b_f, b_cand, b_o, Biasf);

    // fused gemm1: by<8 -> K=3072 (i,f gates), by>=8 -> K=2048 (cand, o-partial)
    k_gemm1<<<dim3(32, 16), 512, 0, stream>>>(xhcb, WT, Biasf, Pre);
    k_cnew<<<4096, 256, 0, stream>>>(Pre, c, Cnewb, out);
    k_gemm2<<<dim3(64, 8), 256, 0, stream>>>(Cnewb, WoCT, Pre, Hnewb, out);
    k_attn<<<512, 256, 0, stream>>>(Hnewb, out, x, memory, u_gs, u_a, u_b, WmT, b_m,
                                    w_a_h, w_a_x, w_a_r, w_b_h, w_b_x, w_b_r, out);
}